// Round 1
// baseline (4976.643 us; speedup 1.0000x reference)
//
#include <hip/hip_runtime.h>
#include <math.h>

// Problem constants (from reference): T=4096, IN=512, K=64, V=64, H=4096
#define T_DIM 4096
#define IN_DIM 512
#define K_DIM 64
#define V_DIM 64
#define H_DIM 4096
#define CHUNKS 256
#define CLEN 16   // T_DIM / CHUNKS

// ---------------- activations ----------------
// phi(x) = 1 + elu(x) = x>0 ? x+1 : exp(x)   (jax elu uses expm1; match it)
__device__ __forceinline__ float phi_act(float v){
    return v > 0.f ? (v + 1.f) : (expm1f(v) + 1.f);
}
// mish(x) = x * tanh(softplus(x)); softplus = max(x,0)+log1p(exp(-|x|)) (stable, == jax logaddexp(x,0))
__device__ __forceinline__ float mish_act(float v){
    float sp = fmaxf(v, 0.f) + log1pf(expf(-fabsf(v)));
    return v * tanhf(sp);
}

// ---------------- generic fp32 GEMM:  Y[M x N] = act(A @ B^T + bias0 + bias1) ----------------
// B stored row-major as (N x Kd) so B^T is the natural "weight.T" layout.
// Supports two K-segments so h3 = h2@W3^T + x@Wskip^T can be one kernel.
// 64x64 block tile, BK=16, 256 threads, 4x4 microtile per thread. All dims multiples of 64/16.
__global__ __launch_bounds__(256) void gemm_xwt(
    const float* __restrict__ A0, const float* __restrict__ B0, int K0,
    const float* __restrict__ A1, const float* __restrict__ B1, int K1,
    const float* __restrict__ bias0, const float* __restrict__ bias1,
    float* __restrict__ Y, int N, int act)
{
    __shared__ float As[16][68];  // [k][m], pad 68 keeps 16B alignment for float4 reads, <=2-way bank conflict
    __shared__ float Bs[16][68];  // [k][n]
    const int tid  = threadIdx.x;
    const int bm   = blockIdx.x * 64;
    const int bn   = blockIdx.y * 64;
    const int lrow = tid >> 2;         // 0..63 : row being staged
    const int lk4  = (tid & 3) * 4;    // 0,4,8,12 : k sub-offset (float4)
    const int tm   = (tid >> 4) * 4;   // 0..60
    const int tn   = (tid & 15) * 4;   // 0..60
    float acc[4][4] = {};

    for (int seg = 0; seg < 2; ++seg){
        const float* A = seg ? A1 : A0;
        const float* B = seg ? B1 : B0;
        const int Kd   = seg ? K1 : K0;
        if (Kd <= 0 || A == nullptr) continue;
        const float* aptr = A + (size_t)(bm + lrow) * Kd + lk4;
        const float* bptr = B + (size_t)(bn + lrow) * Kd + lk4;
        for (int k0 = 0; k0 < Kd; k0 += 16){
            const float4 av = *(const float4*)(aptr + k0);
            const float4 bv = *(const float4*)(bptr + k0);
            __syncthreads();   // previous tile's LDS reads must finish before overwrite
            As[lk4+0][lrow]=av.x; As[lk4+1][lrow]=av.y; As[lk4+2][lrow]=av.z; As[lk4+3][lrow]=av.w;
            Bs[lk4+0][lrow]=bv.x; Bs[lk4+1][lrow]=bv.y; Bs[lk4+2][lrow]=bv.z; Bs[lk4+3][lrow]=bv.w;
            __syncthreads();
            #pragma unroll
            for (int kk = 0; kk < 16; ++kk){
                const float4 a = *(const float4*)&As[kk][tm];
                const float4 b = *(const float4*)&Bs[kk][tn];
                acc[0][0] += a.x*b.x; acc[0][1] += a.x*b.y; acc[0][2] += a.x*b.z; acc[0][3] += a.x*b.w;
                acc[1][0] += a.y*b.x; acc[1][1] += a.y*b.y; acc[1][2] += a.y*b.z; acc[1][3] += a.y*b.w;
                acc[2][0] += a.z*b.x; acc[2][1] += a.z*b.y; acc[2][2] += a.z*b.z; acc[2][3] += a.z*b.w;
                acc[3][0] += a.w*b.x; acc[3][1] += a.w*b.y; acc[3][2] += a.w*b.z; acc[3][3] += a.w*b.w;
            }
        }
    }

    float badd[4] = {0.f, 0.f, 0.f, 0.f};
    if (bias0){
        badd[0] = bias0[bn+tn+0]; badd[1] = bias0[bn+tn+1];
        badd[2] = bias0[bn+tn+2]; badd[3] = bias0[bn+tn+3];
    }
    if (bias1){
        badd[0] += bias1[bn+tn+0]; badd[1] += bias1[bn+tn+1];
        badd[2] += bias1[bn+tn+2]; badd[3] += bias1[bn+tn+3];
    }
    #pragma unroll
    for (int i = 0; i < 4; ++i){
        float r0 = acc[i][0] + badd[0];
        float r1 = acc[i][1] + badd[1];
        float r2 = acc[i][2] + badd[2];
        float r3 = acc[i][3] + badd[3];
        if (act == 1){ r0 = phi_act(r0); r1 = phi_act(r1); r2 = phi_act(r2); r3 = phi_act(r3); }
        else if (act == 2){ r0 = mish_act(r0); r1 = mish_act(r1); r2 = mish_act(r2); r3 = mish_act(r3); }
        *(float4*)&Y[(size_t)(bm + tm + i) * N + bn + tn] = make_float4(r0, r1, r2, r3);
    }
}

// ---------------- segmented scan, pass A: per-chunk local scan summaries ----------------
// State s (64x64) distributed: thread tid owns column j=tid>>2, rows i in [ (tid&3)*16, +16 ).
__global__ __launch_bounds__(256) void scan_passA(
    const float* __restrict__ kbuf, const float* __restrict__ vbuf,
    const int* __restrict__ start,
    float* __restrict__ chunkS, float* __restrict__ chunkZ, int* __restrict__ chunkFlag)
{
    const int c   = blockIdx.x;
    const int tid = threadIdx.x;
    const int j   = tid >> 2;
    const int i0  = (tid & 3) * 16;
    __shared__ float k_lds[64], v_lds[64];
    float s_loc[16];
    #pragma unroll
    for (int e = 0; e < 16; ++e) s_loc[e] = 0.f;
    float z_loc = 0.f;
    int flag = 0;
    const int t0 = c * CLEN;
    for (int tt = 0; tt < CLEN; ++tt){
        const int t = t0 + tt;
        if (tid < 64)       k_lds[tid]      = kbuf[(size_t)t*K_DIM + tid];
        else if (tid < 128) v_lds[tid - 64] = vbuf[(size_t)t*V_DIM + tid - 64];
        __syncthreads();
        const int st = start[t];
        if (st){
            #pragma unroll
            for (int e = 0; e < 16; ++e) s_loc[e] = 0.f;
            z_loc = 0.f;
            flag = 1;
        }
        const float vj = v_lds[j];
        #pragma unroll
        for (int e = 0; e < 16; ++e) s_loc[e] += k_lds[i0 + e] * vj;
        if (tid < 64) z_loc += k_lds[tid];
        __syncthreads();
    }
    #pragma unroll
    for (int e = 0; e < 16; ++e) chunkS[(size_t)c*4096 + (i0 + e)*64 + j] = s_loc[e];
    if (tid < 64) chunkZ[c*64 + tid] = z_loc;
    if (tid == 0) chunkFlag[c] = flag;
}

// ---------------- pass B: exclusive cross-chunk combine, parallel over the 4096 state elems ----------------
__global__ __launch_bounds__(256) void scan_passB(
    const float* __restrict__ chunkS, const float* __restrict__ chunkZ, const int* __restrict__ chunkFlag,
    const float* __restrict__ s0, const float* __restrict__ z0,
    float* __restrict__ carryS, float* __restrict__ carryZ)
{
    const int ij = blockIdx.x * 256 + threadIdx.x;  // 0..4095
    float e = s0[ij];
    for (int c = 0; c < CHUNKS; ++c){
        carryS[(size_t)c*4096 + ij] = e;
        const int f   = chunkFlag[c];
        const float s = chunkS[(size_t)c*4096 + ij];
        e = f ? s : (e + s);
    }
    if (ij < 64){
        float ez = z0[ij];
        for (int c = 0; c < CHUNKS; ++c){
            carryZ[c*64 + ij] = ez;
            const int f   = chunkFlag[c];
            const float z = chunkZ[c*64 + ij];
            ez = f ? z : (ez + z);
        }
    }
}

// ---------------- pass C: replay with carry; emit s[t], z[t], and attention out[t] ----------------
// out[t,j] = (sum_i s[t,i,j]*q[t,i]) / max( (sum_i z[t,i]) * (sum_j q[t,j]), 1e-6 )
__global__ __launch_bounds__(256) void scan_passC(
    const float* __restrict__ kbuf, const float* __restrict__ vbuf, const float* __restrict__ qbuf,
    const int* __restrict__ start,
    const float* __restrict__ carryS, const float* __restrict__ carryZ,
    float* __restrict__ s_out, float* __restrict__ z_out, float* __restrict__ attout)
{
    const int c   = blockIdx.x;
    const int tid = threadIdx.x;
    const int j   = tid >> 2;
    const int g   = tid & 3;
    const int i0  = g * 16;
    __shared__ float k_lds[64], v_lds[64], q_lds[64];
    __shared__ float numer_lds[64];
    __shared__ float stage[4096];
    float s_loc[16];
    #pragma unroll
    for (int e = 0; e < 16; ++e) s_loc[e] = carryS[(size_t)c*4096 + (i0 + e)*64 + j];
    float z_loc = (tid < 64) ? carryZ[c*64 + tid] : 0.f;

    const int t0 = c * CLEN;
    for (int tt = 0; tt < CLEN; ++tt){
        const int t = t0 + tt;
        if (tid < 64)       k_lds[tid]       = kbuf[(size_t)t*K_DIM + tid];
        else if (tid < 128) v_lds[tid - 64]  = vbuf[(size_t)t*V_DIM + tid - 64];
        else if (tid < 192) q_lds[tid - 128] = qbuf[(size_t)t*K_DIM + tid - 128];
        __syncthreads();
        const int st = start[t];
        if (st){
            #pragma unroll
            for (int e = 0; e < 16; ++e) s_loc[e] = 0.f;
        }
        const float vj = v_lds[j];
        float np = 0.f;
        #pragma unroll
        for (int e = 0; e < 16; ++e){
            s_loc[e] += k_lds[i0 + e] * vj;
            np += s_loc[e] * q_lds[i0 + e];
        }
        // reduce numer partial across the 4 g-lanes (consecutive lanes, same j)
        np += __shfl_down(np, 1, 64);
        np += __shfl_down(np, 2, 64);
        if (g == 0) numer_lds[j] = np;
        float denom = 1.f;
        if (tid < 64){  // wave 0: z update + Zsum/Qsum reductions
            z_loc = (st ? 0.f : z_loc) + k_lds[tid];
            z_out[(size_t)t*K_DIM + tid] = z_loc;
            float zs = z_loc;
            float qs = q_lds[tid];
            #pragma unroll
            for (int o = 32; o > 0; o >>= 1){
                zs += __shfl_down(zs, o, 64);
                qs += __shfl_down(qs, o, 64);
            }
            zs = __shfl(zs, 0, 64);
            qs = __shfl(qs, 0, 64);
            denom = fmaxf(zs * qs, 1e-6f);
        }
        #pragma unroll
        for (int e = 0; e < 16; ++e) stage[(i0 + e)*64 + j] = s_loc[e];
        __syncthreads();
        // coalesced dump of s[t] (16 KB) via float4
        float4* so = (float4*)(s_out + (size_t)t*4096);
        const float4* stv = (const float4*)stage;
        #pragma unroll
        for (int r = 0; r < 4; ++r) so[tid + 256*r] = stv[tid + 256*r];
        if (tid < 64) attout[(size_t)t*V_DIM + tid] = numer_lds[tid] / denom;
        __syncthreads();  // protect stage/numer/k_lds before next iteration's writes
    }
}

// ---------------- LayerNorm over H=4096, in place, one block per row ----------------
__global__ __launch_bounds__(256) void ln_kernel(
    float* __restrict__ h, const float* __restrict__ g, const float* __restrict__ b)
{
    __shared__ float sm[4];
    const int t   = blockIdx.x;
    const int tid = threadIdx.x;
    float* row = h + (size_t)t * H_DIM;
    float4 v[4];
    float s = 0.f;
    #pragma unroll
    for (int r = 0; r < 4; ++r){
        v[r] = ((const float4*)row)[tid + 256*r];
        s += v[r].x + v[r].y + v[r].z + v[r].w;
    }
    #pragma unroll
    for (int o = 32; o > 0; o >>= 1) s += __shfl_down(s, o, 64);
    if ((tid & 63) == 0) sm[tid >> 6] = s;
    __syncthreads();
    const float mu = (sm[0] + sm[1] + sm[2] + sm[3]) * (1.f / H_DIM);
    __syncthreads();
    float sq = 0.f;
    #pragma unroll
    for (int r = 0; r < 4; ++r){
        float dx = v[r].x - mu, dy = v[r].y - mu, dz = v[r].z - mu, dw = v[r].w - mu;
        sq += dx*dx + dy*dy + dz*dz + dw*dw;
    }
    #pragma unroll
    for (int o = 32; o > 0; o >>= 1) sq += __shfl_down(sq, o, 64);
    if ((tid & 63) == 0) sm[tid >> 6] = sq;
    __syncthreads();
    const float var = (sm[0] + sm[1] + sm[2] + sm[3]) * (1.f / H_DIM);
    const float inv = rsqrtf(var + 1e-5f);
    #pragma unroll
    for (int r = 0; r < 4; ++r){
        const int i4 = tid + 256*r;
        const float4 gg = ((const float4*)g)[i4];
        const float4 bb = ((const float4*)b)[i4];
        float4 o;
        o.x = (v[r].x - mu) * inv * gg.x + bb.x;
        o.y = (v[r].y - mu) * inv * gg.y + bb.y;
        o.z = (v[r].z - mu) * inv * gg.z + bb.z;
        o.w = (v[r].w - mu) * inv * gg.w + bb.w;
        ((float4*)row)[i4] = o;
    }
}

extern "C" void kernel_launch(void* const* d_in, const int* in_sizes, int n_in,
                              void* d_out, int out_size, void* d_ws, size_t ws_size,
                              hipStream_t stream)
{
    (void)in_sizes; (void)n_in; (void)out_size; (void)ws_size;
    const float* x     = (const float*)d_in[0];
    const float* s0    = (const float*)d_in[1];
    const float* z0    = (const float*)d_in[2];
    const int*   start = (const int*)d_in[3];   // bool -> int32 per harness convention
    /* d_in[4] next_done: carried through the scan but never read in outputs */
    const float* Wk    = (const float*)d_in[5];
    const float* Wq    = (const float*)d_in[6];
    const float* Wv    = (const float*)d_in[7];
    const float* bv    = (const float*)d_in[8];
    const float* Wskip = (const float*)d_in[9];
    const float* bskip = (const float*)d_in[10];
    const float* W1    = (const float*)d_in[11];
    const float* b1    = (const float*)d_in[12];
    const float* W2    = (const float*)d_in[13];
    const float* b2    = (const float*)d_in[14];
    const float* W3    = (const float*)d_in[15];
    const float* b3    = (const float*)d_in[16];
    const float* ln_g  = (const float*)d_in[17];
    const float* ln_b  = (const float*)d_in[18];

    // workspace layout (floats); total ~36.7M floats (~140 MB)
    float* ws     = (float*)d_ws;
    float* kbuf   = ws;
    float* qbuf   = kbuf   + (size_t)T_DIM * K_DIM;      // 262144
    float* vbuf   = qbuf   + (size_t)T_DIM * K_DIM;
    float* attbuf = vbuf   + (size_t)T_DIM * V_DIM;
    float* chS    = attbuf + (size_t)T_DIM * V_DIM;      // CHUNKS*4096
    float* chZ    = chS    + (size_t)CHUNKS * 4096;
    float* caS    = chZ    + (size_t)CHUNKS * 64;
    float* caZ    = caS    + (size_t)CHUNKS * 4096;
    int*   flags  = (int*)(caZ + (size_t)CHUNKS * 64);
    float* h1buf  = (float*)(flags + CHUNKS);
    float* h2buf  = h1buf  + (size_t)T_DIM * H_DIM;

    float* hn    = (float*)d_out;                        // (T,H)
    float* s_o   = hn  + (size_t)T_DIM * H_DIM;          // (T,K,V)
    float* z_o   = s_o + (size_t)T_DIM * K_DIM * V_DIM;  // (T,1,K)

    // 1) projections: k = phi(x@Wk^T), q = phi(x@Wq^T), v = x@Wv^T + bv
    gemm_xwt<<<dim3(T_DIM/64, K_DIM/64), 256, 0, stream>>>(
        x, Wk, IN_DIM, nullptr, nullptr, 0, nullptr, nullptr, kbuf, K_DIM, 1);
    gemm_xwt<<<dim3(T_DIM/64, K_DIM/64), 256, 0, stream>>>(
        x, Wq, IN_DIM, nullptr, nullptr, 0, nullptr, nullptr, qbuf, K_DIM, 1);
    gemm_xwt<<<dim3(T_DIM/64, V_DIM/64), 256, 0, stream>>>(
        x, Wv, IN_DIM, nullptr, nullptr, 0, bv, nullptr, vbuf, V_DIM, 0);

    // 2) segmented scan (3 passes)
    scan_passA<<<CHUNKS, 256, 0, stream>>>(kbuf, vbuf, start, chS, chZ, flags);
    scan_passB<<<4096/256, 256, 0, stream>>>(chS, chZ, flags, s0, z0, caS, caZ);
    scan_passC<<<CHUNKS, 256, 0, stream>>>(kbuf, vbuf, qbuf, start, caS, caZ, s_o, z_o, attbuf);

    // 3) MLP
    gemm_xwt<<<dim3(T_DIM/64, H_DIM/64), 256, 0, stream>>>(
        attbuf, W1, V_DIM, nullptr, nullptr, 0, b1, nullptr, h1buf, H_DIM, 2);
    gemm_xwt<<<dim3(T_DIM/64, H_DIM/64), 256, 0, stream>>>(
        h1buf, W2, H_DIM, nullptr, nullptr, 0, b2, nullptr, h2buf, H_DIM, 2);
    // h3 = h2@W3^T + b3 + x@Wskip^T + bskip  (two K-segments, straight into d_out)
    gemm_xwt<<<dim3(T_DIM/64, H_DIM/64), 256, 0, stream>>>(
        h2buf, W3, H_DIM, x, Wskip, IN_DIM, b3, bskip, hn, H_DIM, 0);

    // 4) LayerNorm in place on d_out
    ln_kernel<<<T_DIM, 256, 0, stream>>>(hn, ln_g, ln_b);
}

// Round 2
// 1021.698 us; speedup vs baseline: 4.8710x; 4.8710x over previous
//
#include <hip/hip_runtime.h>
#include <math.h>

// Problem constants (from reference): T=4096, IN=512, K=64, V=64, H=4096
#define T_DIM 4096
#define IN_DIM 512
#define K_DIM 64
#define V_DIM 64
#define H_DIM 4096
#define CHUNKS 256
#define CLEN 16   // T_DIM / CHUNKS

typedef __attribute__((ext_vector_type(8))) short short8;  // 8 bf16 = 4 VGPRs
typedef __attribute__((ext_vector_type(4))) float f32x4;

// ---------------- activations ----------------
__device__ __forceinline__ float phi_act(float v){
    return v > 0.f ? (v + 1.f) : (expm1f(v) + 1.f);
}
__device__ __forceinline__ float mish_act(float v){
    float sp = fmaxf(v, 0.f) + log1pf(expf(-fabsf(v)));
    return v * tanhf(sp);
}
// fp32 -> bf16 round-to-nearest-even (bit trick)
__device__ __forceinline__ unsigned short f2bf(float f){
    union { float f; unsigned int u; } x; x.f = f;
    unsigned int u = x.u + 0x7fffu + ((x.u >> 16) & 1u);
    return (unsigned short)(u >> 16);
}

// async 16B global->LDS (dest = wave-uniform base + lane*16; layout must be contiguous per lane)
__device__ __forceinline__ void async16(const unsigned short* g, unsigned short* l){
    __builtin_amdgcn_global_load_lds(
        (const __attribute__((address_space(1))) unsigned int*)g,
        (__attribute__((address_space(3))) unsigned int*)l,
        16, 0, 0);
}

// ---------------- fp32 -> bf16 conversion, 4 elems/thread ----------------
__global__ __launch_bounds__(256) void cvt_bf16(const float* __restrict__ in,
                                                unsigned short* __restrict__ out, int n4){
    int i = blockIdx.x * 256 + threadIdx.x;
    if (i >= n4) return;
    float4 v = ((const float4*)in)[i];
    ushort4 o;
    o.x = f2bf(v.x); o.y = f2bf(v.y); o.z = f2bf(v.z); o.w = f2bf(v.w);
    ((ushort4*)out)[i] = o;
}

// ---------------- bf16 MFMA GEMM:  Y[M x N] = act(A @ B^T + bias0 + bias1) ----------------
// A: (M x Kd) bf16 row-major; B: (N x Kd) bf16 row-major (weight layout -> B^T GEMM).
// 128x128 block tile, BK=64, 256 threads = 4 waves, each wave a 64x64 quadrant (4x4 subtiles
// of mfma_f32_16x16x32_bf16). global_load_lds width-16 staging (m97 structure).
// Two K-segments so h3 = h2@W3^T + x@Wskip^T is one kernel. N passed explicitly.
__global__ __launch_bounds__(256) void gemm_mfma_bt(
    const unsigned short* __restrict__ A0, const unsigned short* __restrict__ B0, int K0,
    const unsigned short* __restrict__ A1, const unsigned short* __restrict__ B1, int K1,
    const float* __restrict__ bias0, const float* __restrict__ bias1,
    void* __restrict__ Y, int N, int act, int out_bf16)
{
    constexpr int BK = 64;
    __shared__ unsigned short As[128 * BK];   // [row][k], contiguous (no pad: global_load_lds)
    __shared__ unsigned short Bs[128 * BK];
    const int tid  = threadIdx.x;
    const int lane = tid & 63;
    const int wm   = (tid >> 6 & 1) * 64;     // wave m-offset in tile
    const int wn   = (tid >> 7) * 64;         // wave n-offset in tile
    const int bm   = blockIdx.x * 128;
    const int bn   = blockIdx.y * 128;
    const int l15  = lane & 15;
    const int quad = lane >> 4;

    f32x4 acc[4][4] = {};

    for (int seg = 0; seg < 2; ++seg){
        const unsigned short* A = seg ? A1 : A0;
        const unsigned short* B = seg ? B1 : B0;
        const int Kd = seg ? K1 : K0;
        if (Kd <= 0 || A == nullptr) continue;
        for (int k0 = 0; k0 < Kd; k0 += BK){
            __syncthreads();  // previous tile's ds_reads must drain before restage
            #pragma unroll
            for (int it = 0; it < 4; ++it){   // 1024 chunks of 16B per matrix, 4 per thread
                const int c = it * 256 + tid;     // chunk index; LDS offset = c*16B (lane-contig)
                const int r = c >> 3;             // row 0..127
                const int ko = (c & 7) * 8;       // k sub-offset
                async16(A + (size_t)(bm + r) * Kd + k0 + ko, &As[c * 8]);
            }
            #pragma unroll
            for (int it = 0; it < 4; ++it){
                const int c = it * 256 + tid;
                const int r = c >> 3;
                const int ko = (c & 7) * 8;
                async16(B + (size_t)(bn + r) * Kd + k0 + ko, &Bs[c * 8]);
            }
            __syncthreads();  // emits s_waitcnt vmcnt(0) before s_barrier -> staging complete
            #pragma unroll
            for (int ks = 0; ks < 2; ++ks){
                short8 af[4], bf[4];
                #pragma unroll
                for (int mi = 0; mi < 4; ++mi)
                    af[mi] = *(const short8*)&As[(wm + mi * 16 + l15) * BK + ks * 32 + quad * 8];
                #pragma unroll
                for (int ni = 0; ni < 4; ++ni)
                    bf[ni] = *(const short8*)&Bs[(wn + ni * 16 + l15) * BK + ks * 32 + quad * 8];
                #pragma unroll
                for (int mi = 0; mi < 4; ++mi)
                    #pragma unroll
                    for (int ni = 0; ni < 4; ++ni)
                        acc[mi][ni] = __builtin_amdgcn_mfma_f32_16x16x32_bf16(
                            af[mi], bf[ni], acc[mi][ni], 0, 0, 0);
            }
        }
    }

    // epilogue: C/D mapping col=lane&15, row=quad*4+reg
    #pragma unroll
    for (int ni = 0; ni < 4; ++ni){
        const int col = bn + wn + ni * 16 + l15;
        float bb = 0.f;
        if (bias0) bb += bias0[col];
        if (bias1) bb += bias1[col];
        #pragma unroll
        for (int mi = 0; mi < 4; ++mi){
            #pragma unroll
            for (int r = 0; r < 4; ++r){
                const int row = bm + wm + mi * 16 + quad * 4 + r;
                float v = acc[mi][ni][r] + bb;
                if (act == 2) v = mish_act(v);
                if (out_bf16) ((unsigned short*)Y)[(size_t)row * N + col] = f2bf(v);
                else          ((float*)Y)[(size_t)row * N + col] = v;
            }
        }
    }
}

// ---------------- fp32 GEMM (small projections):  Y = act(x @ W^T [+ bias]) ----------------
__global__ __launch_bounds__(256) void gemm_xwt(
    const float* __restrict__ A0, const float* __restrict__ B0, int K0,
    const float* __restrict__ bias0,
    float* __restrict__ Y, int N, int act)
{
    __shared__ float As[16][68];
    __shared__ float Bs[16][68];
    const int tid  = threadIdx.x;
    const int bm   = blockIdx.x * 64;
    const int bn   = blockIdx.y * 64;
    const int lrow = tid >> 2;
    const int lk4  = (tid & 3) * 4;
    const int tm   = (tid >> 4) * 4;
    const int tn   = (tid & 15) * 4;
    float acc[4][4] = {};

    const float* aptr = A0 + (size_t)(bm + lrow) * K0 + lk4;
    const float* bptr = B0 + (size_t)(bn + lrow) * K0 + lk4;
    for (int k0 = 0; k0 < K0; k0 += 16){
        const float4 av = *(const float4*)(aptr + k0);
        const float4 bv = *(const float4*)(bptr + k0);
        __syncthreads();
        As[lk4+0][lrow]=av.x; As[lk4+1][lrow]=av.y; As[lk4+2][lrow]=av.z; As[lk4+3][lrow]=av.w;
        Bs[lk4+0][lrow]=bv.x; Bs[lk4+1][lrow]=bv.y; Bs[lk4+2][lrow]=bv.z; Bs[lk4+3][lrow]=bv.w;
        __syncthreads();
        #pragma unroll
        for (int kk = 0; kk < 16; ++kk){
            const float4 a = *(const float4*)&As[kk][tm];
            const float4 b = *(const float4*)&Bs[kk][tn];
            acc[0][0] += a.x*b.x; acc[0][1] += a.x*b.y; acc[0][2] += a.x*b.z; acc[0][3] += a.x*b.w;
            acc[1][0] += a.y*b.x; acc[1][1] += a.y*b.y; acc[1][2] += a.y*b.z; acc[1][3] += a.y*b.w;
            acc[2][0] += a.z*b.x; acc[2][1] += a.z*b.y; acc[2][2] += a.z*b.z; acc[2][3] += a.z*b.w;
            acc[3][0] += a.w*b.x; acc[3][1] += a.w*b.y; acc[3][2] += a.w*b.z; acc[3][3] += a.w*b.w;
        }
    }
    float badd[4] = {0.f, 0.f, 0.f, 0.f};
    if (bias0){
        badd[0] = bias0[bn+tn+0]; badd[1] = bias0[bn+tn+1];
        badd[2] = bias0[bn+tn+2]; badd[3] = bias0[bn+tn+3];
    }
    #pragma unroll
    for (int i = 0; i < 4; ++i){
        float r0 = acc[i][0] + badd[0];
        float r1 = acc[i][1] + badd[1];
        float r2 = acc[i][2] + badd[2];
        float r3 = acc[i][3] + badd[3];
        if (act == 1){ r0 = phi_act(r0); r1 = phi_act(r1); r2 = phi_act(r2); r3 = phi_act(r3); }
        *(float4*)&Y[(size_t)(bm + tm + i) * N + bn + tn] = make_float4(r0, r1, r2, r3);
    }
}

// ---------------- segmented scan, pass A ----------------
__global__ __launch_bounds__(256) void scan_passA(
    const float* __restrict__ kbuf, const float* __restrict__ vbuf,
    const int* __restrict__ start,
    float* __restrict__ chunkS, float* __restrict__ chunkZ, int* __restrict__ chunkFlag)
{
    const int c   = blockIdx.x;
    const int tid = threadIdx.x;
    const int j   = tid >> 2;
    const int i0  = (tid & 3) * 16;
    __shared__ float k_lds[64], v_lds[64];
    float s_loc[16];
    #pragma unroll
    for (int e = 0; e < 16; ++e) s_loc[e] = 0.f;
    float z_loc = 0.f;
    int flag = 0;
    const int t0 = c * CLEN;
    for (int tt = 0; tt < CLEN; ++tt){
        const int t = t0 + tt;
        if (tid < 64)       k_lds[tid]      = kbuf[(size_t)t*K_DIM + tid];
        else if (tid < 128) v_lds[tid - 64] = vbuf[(size_t)t*V_DIM + tid - 64];
        __syncthreads();
        const int st = start[t];
        if (st){
            #pragma unroll
            for (int e = 0; e < 16; ++e) s_loc[e] = 0.f;
            z_loc = 0.f;
            flag = 1;
        }
        const float vj = v_lds[j];
        #pragma unroll
        for (int e = 0; e < 16; ++e) s_loc[e] += k_lds[i0 + e] * vj;
        if (tid < 64) z_loc += k_lds[tid];
        __syncthreads();
    }
    #pragma unroll
    for (int e = 0; e < 16; ++e) chunkS[(size_t)c*4096 + (i0 + e)*64 + j] = s_loc[e];
    if (tid < 64) chunkZ[c*64 + tid] = z_loc;
    if (tid == 0) chunkFlag[c] = flag;
}

// ---------------- pass B: exclusive cross-chunk combine ----------------
__global__ __launch_bounds__(256) void scan_passB(
    const float* __restrict__ chunkS, const float* __restrict__ chunkZ, const int* __restrict__ chunkFlag,
    const float* __restrict__ s0, const float* __restrict__ z0,
    float* __restrict__ carryS, float* __restrict__ carryZ)
{
    const int ij = blockIdx.x * 256 + threadIdx.x;
    float e = s0[ij];
    for (int c = 0; c < CHUNKS; ++c){
        carryS[(size_t)c*4096 + ij] = e;
        const int f   = chunkFlag[c];
        const float s = chunkS[(size_t)c*4096 + ij];
        e = f ? s : (e + s);
    }
    if (ij < 64){
        float ez = z0[ij];
        for (int c = 0; c < CHUNKS; ++c){
            carryZ[c*64 + ij] = ez;
            const int f   = chunkFlag[c];
            const float z = chunkZ[c*64 + ij];
            ez = f ? z : (ez + z);
        }
    }
}

// ---------------- pass C: replay with carry; emit s[t], z[t], att out (bf16) ----------------
__global__ __launch_bounds__(256) void scan_passC(
    const float* __restrict__ kbuf, const float* __restrict__ vbuf, const float* __restrict__ qbuf,
    const int* __restrict__ start,
    const float* __restrict__ carryS, const float* __restrict__ carryZ,
    float* __restrict__ s_out, float* __restrict__ z_out, unsigned short* __restrict__ attout)
{
    const int c   = blockIdx.x;
    const int tid = threadIdx.x;
    const int j   = tid >> 2;
    const int g   = tid & 3;
    const int i0  = g * 16;
    __shared__ float k_lds[64], v_lds[64], q_lds[64];
    __shared__ float numer_lds[64];
    __shared__ float stage[4096];
    float s_loc[16];
    #pragma unroll
    for (int e = 0; e < 16; ++e) s_loc[e] = carryS[(size_t)c*4096 + (i0 + e)*64 + j];
    float z_loc = (tid < 64) ? carryZ[c*64 + tid] : 0.f;

    const int t0 = c * CLEN;
    for (int tt = 0; tt < CLEN; ++tt){
        const int t = t0 + tt;
        if (tid < 64)       k_lds[tid]       = kbuf[(size_t)t*K_DIM + tid];
        else if (tid < 128) v_lds[tid - 64]  = vbuf[(size_t)t*V_DIM + tid - 64];
        else if (tid < 192) q_lds[tid - 128] = qbuf[(size_t)t*K_DIM + tid - 128];
        __syncthreads();
        const int st = start[t];
        if (st){
            #pragma unroll
            for (int e = 0; e < 16; ++e) s_loc[e] = 0.f;
        }
        const float vj = v_lds[j];
        float np = 0.f;
        #pragma unroll
        for (int e = 0; e < 16; ++e){
            s_loc[e] += k_lds[i0 + e] * vj;
            np += s_loc[e] * q_lds[i0 + e];
        }
        np += __shfl_down(np, 1, 64);
        np += __shfl_down(np, 2, 64);
        if (g == 0) numer_lds[j] = np;
        float denom = 1.f;
        if (tid < 64){
            z_loc = (st ? 0.f : z_loc) + k_lds[tid];
            z_out[(size_t)t*K_DIM + tid] = z_loc;
            float zs = z_loc;
            float qs = q_lds[tid];
            #pragma unroll
            for (int o = 32; o > 0; o >>= 1){
                zs += __shfl_down(zs, o, 64);
                qs += __shfl_down(qs, o, 64);
            }
            zs = __shfl(zs, 0, 64);
            qs = __shfl(qs, 0, 64);
            denom = fmaxf(zs * qs, 1e-6f);
        }
        #pragma unroll
        for (int e = 0; e < 16; ++e) stage[(i0 + e)*64 + j] = s_loc[e];
        __syncthreads();
        float4* so = (float4*)(s_out + (size_t)t*4096);
        const float4* stv = (const float4*)stage;
        #pragma unroll
        for (int r = 0; r < 4; ++r) so[tid + 256*r] = stv[tid + 256*r];
        if (tid < 64) attout[(size_t)t*V_DIM + tid] = f2bf(numer_lds[tid] / denom);
        __syncthreads();
    }
}

// ---------------- LayerNorm over H=4096, in place ----------------
__global__ __launch_bounds__(256) void ln_kernel(
    float* __restrict__ h, const float* __restrict__ g, const float* __restrict__ b)
{
    __shared__ float sm[4];
    const int t   = blockIdx.x;
    const int tid = threadIdx.x;
    float* row = h + (size_t)t * H_DIM;
    float4 v[4];
    float s = 0.f;
    #pragma unroll
    for (int r = 0; r < 4; ++r){
        v[r] = ((const float4*)row)[tid + 256*r];
        s += v[r].x + v[r].y + v[r].z + v[r].w;
    }
    #pragma unroll
    for (int o = 32; o > 0; o >>= 1) s += __shfl_down(s, o, 64);
    if ((tid & 63) == 0) sm[tid >> 6] = s;
    __syncthreads();
    const float mu = (sm[0] + sm[1] + sm[2] + sm[3]) * (1.f / H_DIM);
    __syncthreads();
    float sq = 0.f;
    #pragma unroll
    for (int r = 0; r < 4; ++r){
        float dx = v[r].x - mu, dy = v[r].y - mu, dz = v[r].z - mu, dw = v[r].w - mu;
        sq += dx*dx + dy*dy + dz*dz + dw*dw;
    }
    #pragma unroll
    for (int o = 32; o > 0; o >>= 1) sq += __shfl_down(sq, o, 64);
    if ((tid & 63) == 0) sm[tid >> 6] = sq;
    __syncthreads();
    const float var = (sm[0] + sm[1] + sm[2] + sm[3]) * (1.f / H_DIM);
    const float inv = rsqrtf(var + 1e-5f);
    #pragma unroll
    for (int r = 0; r < 4; ++r){
        const int i4 = tid + 256*r;
        const float4 gg = ((const float4*)g)[i4];
        const float4 bb = ((const float4*)b)[i4];
        float4 o;
        o.x = (v[r].x - mu) * inv * gg.x + bb.x;
        o.y = (v[r].y - mu) * inv * gg.y + bb.y;
        o.z = (v[r].z - mu) * inv * gg.z + bb.z;
        o.w = (v[r].w - mu) * inv * gg.w + bb.w;
        ((float4*)row)[i4] = o;
    }
}

extern "C" void kernel_launch(void* const* d_in, const int* in_sizes, int n_in,
                              void* d_out, int out_size, void* d_ws, size_t ws_size,
                              hipStream_t stream)
{
    (void)in_sizes; (void)n_in; (void)out_size; (void)ws_size;
    const float* x     = (const float*)d_in[0];
    const float* s0    = (const float*)d_in[1];
    const float* z0    = (const float*)d_in[2];
    const int*   start = (const int*)d_in[3];
    const float* Wk    = (const float*)d_in[5];
    const float* Wq    = (const float*)d_in[6];
    const float* Wv    = (const float*)d_in[7];
    const float* bv    = (const float*)d_in[8];
    const float* Wskip = (const float*)d_in[9];
    const float* bskip = (const float*)d_in[10];
    const float* W1    = (const float*)d_in[11];
    const float* b1    = (const float*)d_in[12];
    const float* W2    = (const float*)d_in[13];
    const float* b2    = (const float*)d_in[14];
    const float* W3    = (const float*)d_in[15];
    const float* b3    = (const float*)d_in[16];
    const float* ln_g  = (const float*)d_in[17];
    const float* ln_b  = (const float*)d_in[18];

    // ---- workspace carve (256B-aligned), total ~148 MB ----
    char* p = (char*)d_ws;
    auto alloc = [&](size_t bytes) -> void* {
        void* r = (void*)p; p += (bytes + 255) & ~(size_t)255; return r;
    };
    float* kbuf  = (float*)alloc((size_t)T_DIM * K_DIM * 4);
    float* qbuf  = (float*)alloc((size_t)T_DIM * K_DIM * 4);
    float* vbuf  = (float*)alloc((size_t)T_DIM * V_DIM * 4);
    float* chS   = (float*)alloc((size_t)CHUNKS * 4096 * 4);
    float* chZ   = (float*)alloc((size_t)CHUNKS * 64 * 4);
    float* caS   = (float*)alloc((size_t)CHUNKS * 4096 * 4);
    float* caZ   = (float*)alloc((size_t)CHUNKS * 64 * 4);
    int*   flags = (int*)  alloc((size_t)CHUNKS * 4);
    unsigned short* xb     = (unsigned short*)alloc((size_t)T_DIM * IN_DIM * 2);
    unsigned short* Wskipb = (unsigned short*)alloc((size_t)H_DIM * IN_DIM * 2);
    unsigned short* W1b    = (unsigned short*)alloc((size_t)H_DIM * V_DIM * 2);
    unsigned short* W2b    = (unsigned short*)alloc((size_t)H_DIM * H_DIM * 2);
    unsigned short* W3b    = (unsigned short*)alloc((size_t)H_DIM * H_DIM * 2);
    unsigned short* attb   = (unsigned short*)alloc((size_t)T_DIM * V_DIM * 2);
    unsigned short* h1b    = (unsigned short*)alloc((size_t)T_DIM * H_DIM * 2);
    unsigned short* h2b    = (unsigned short*)alloc((size_t)T_DIM * H_DIM * 2);

    float* hn  = (float*)d_out;                          // (T,H)
    float* s_o = hn  + (size_t)T_DIM * H_DIM;            // (T,K,V)
    float* z_o = s_o + (size_t)T_DIM * K_DIM * V_DIM;    // (T,1,K)

    // 0) bf16 conversions of GEMM inputs (independent; launch up front)
    cvt_bf16<<<(T_DIM*IN_DIM/4 + 255)/256, 256, 0, stream>>>(x, xb, T_DIM*IN_DIM/4);
    cvt_bf16<<<(H_DIM*IN_DIM/4 + 255)/256, 256, 0, stream>>>(Wskip, Wskipb, H_DIM*IN_DIM/4);
    cvt_bf16<<<(H_DIM*V_DIM/4 + 255)/256, 256, 0, stream>>>(W1, W1b, H_DIM*V_DIM/4);
    cvt_bf16<<<(H_DIM*H_DIM/4 + 255)/256, 256, 0, stream>>>(W2, W2b, H_DIM*H_DIM/4);
    cvt_bf16<<<(H_DIM*H_DIM/4 + 255)/256, 256, 0, stream>>>(W3, W3b, H_DIM*H_DIM/4);

    // 1) projections (fp32): k = phi(x@Wk^T), q = phi(x@Wq^T), v = x@Wv^T + bv
    gemm_xwt<<<dim3(T_DIM/64, K_DIM/64), 256, 0, stream>>>(x, Wk, IN_DIM, nullptr, kbuf, K_DIM, 1);
    gemm_xwt<<<dim3(T_DIM/64, K_DIM/64), 256, 0, stream>>>(x, Wq, IN_DIM, nullptr, qbuf, K_DIM, 1);
    gemm_xwt<<<dim3(T_DIM/64, V_DIM/64), 256, 0, stream>>>(x, Wv, IN_DIM, bv, vbuf, V_DIM, 0);

    // 2) segmented scan (3 passes); pass C emits att in bf16
    scan_passA<<<CHUNKS, 256, 0, stream>>>(kbuf, vbuf, start, chS, chZ, flags);
    scan_passB<<<4096/256, 256, 0, stream>>>(chS, chZ, flags, s0, z0, caS, caZ);
    scan_passC<<<CHUNKS, 256, 0, stream>>>(kbuf, vbuf, qbuf, start, caS, caZ, s_o, z_o, attb);

    // 3) MLP on bf16 MFMA
    // h1 = mish(att@W1^T + b1)  -> bf16
    gemm_mfma_bt<<<dim3(T_DIM/128, H_DIM/128), 256, 0, stream>>>(
        attb, W1b, V_DIM, nullptr, nullptr, 0, b1, nullptr, h1b, H_DIM, 2, 1);
    // h2 = mish(h1@W2^T + b2)   -> bf16
    gemm_mfma_bt<<<dim3(T_DIM/128, H_DIM/128), 256, 0, stream>>>(
        h1b, W2b, H_DIM, nullptr, nullptr, 0, b2, nullptr, h2b, H_DIM, 2, 1);
    // h3 = h2@W3^T + b3 + x@Wskip^T + bskip -> fp32 into d_out
    gemm_mfma_bt<<<dim3(T_DIM/128, H_DIM/128), 256, 0, stream>>>(
        h2b, W3b, H_DIM, xb, Wskipb, IN_DIM, b3, bskip, hn, H_DIM, 0, 0);

    // 4) LayerNorm in place on d_out
    ln_kernel<<<T_DIM, 256, 0, stream>>>(hn, ln_g, ln_b);
}

// Round 3
// 948.375 us; speedup vs baseline: 5.2476x; 1.0773x over previous
//
#include <hip/hip_runtime.h>
#include <math.h>

// Problem constants (from reference): T=4096, IN=512, K=64, V=64, H=4096
#define T_DIM 4096
#define IN_DIM 512
#define K_DIM 64
#define V_DIM 64
#define H_DIM 4096
#define CHUNKS 256
#define CLEN 16   // T_DIM / CHUNKS

typedef __attribute__((ext_vector_type(8))) short short8;  // 8 bf16 = 4 VGPRs
typedef __attribute__((ext_vector_type(4))) float f32x4;

// ---------------- activations ----------------
__device__ __forceinline__ float phi_act(float v){
    return v > 0.f ? (v + 1.f) : (expm1f(v) + 1.f);
}
__device__ __forceinline__ float mish_act(float v){
    float sp = fmaxf(v, 0.f) + log1pf(expf(-fabsf(v)));
    return v * tanhf(sp);
}
// fp32 -> bf16 round-to-nearest-even (bit trick)
__device__ __forceinline__ unsigned short f2bf(float f){
    union { float f; unsigned int u; } x; x.f = f;
    unsigned int u = x.u + 0x7fffu + ((x.u >> 16) & 1u);
    return (unsigned short)(u >> 16);
}

// async 16B global->LDS (dest = wave-uniform base + lane*16; layout must be contiguous per lane)
__device__ __forceinline__ void async16(const unsigned short* g, unsigned short* l){
    __builtin_amdgcn_global_load_lds(
        (const __attribute__((address_space(1))) unsigned int*)g,
        (__attribute__((address_space(3))) unsigned int*)l,
        16, 0, 0);
}

// ---------------- fp32 -> bf16 conversion, 4 elems/thread ----------------
__global__ __launch_bounds__(256) void cvt_bf16(const float* __restrict__ in,
                                                unsigned short* __restrict__ out, int n4){
    int i = blockIdx.x * 256 + threadIdx.x;
    if (i >= n4) return;
    float4 v = ((const float4*)in)[i];
    ushort4 o;
    o.x = f2bf(v.x); o.y = f2bf(v.y); o.z = f2bf(v.z); o.w = f2bf(v.w);
    ((ushort4*)out)[i] = o;
}

// ---------------- bf16 MFMA GEMM:  Y[M x N] = act(A @ B^T + bias0 + bias1) ----------------
// A: (M x Kd) bf16 row-major; B: (N x Kd) bf16 row-major (weight layout -> B^T GEMM).
// 128x128 block tile, BK=64, 256 threads = 4 waves, each wave a 64x64 quadrant (4x4 subtiles
// of mfma_f32_16x16x32_bf16). global_load_lds width-16 staging (m97 structure).
// LDS layout XOR-swizzled: row r's k-chunk slot s holds global k-chunk (s ^ (r&7)).
// (row stride is 128 B = 32 banks; without swizzle the 16 l15-lanes of one ds_read_b128
//  all hit one bank = 16-way conflict. Swizzle spreads them over 8 columns -> 2-way = free.)
// Source-side permutation keeps global_load_lds's fixed lane->LDS mapping intact and
// coalescing unchanged (permutes within each row's 128 B segment).
__global__ __launch_bounds__(256) void gemm_mfma_bt(
    const unsigned short* __restrict__ A0, const unsigned short* __restrict__ B0, int K0,
    const unsigned short* __restrict__ A1, const unsigned short* __restrict__ B1, int K1,
    const float* __restrict__ bias0, const float* __restrict__ bias1,
    void* __restrict__ Y, int N, int act, int out_bf16)
{
    constexpr int BK = 64;
    __shared__ unsigned short As[128 * BK];
    __shared__ unsigned short Bs[128 * BK];
    const int tid  = threadIdx.x;
    const int lane = tid & 63;
    const int wm   = (tid >> 6 & 1) * 64;     // wave m-offset in tile
    const int wn   = (tid >> 7) * 64;         // wave n-offset in tile
    const int bm   = blockIdx.x * 128;
    const int bn   = blockIdx.y * 128;
    const int l15  = lane & 15;
    const int quad = lane >> 4;

    f32x4 acc[4][4] = {};

    for (int seg = 0; seg < 2; ++seg){
        const unsigned short* A = seg ? A1 : A0;
        const unsigned short* B = seg ? B1 : B0;
        const int Kd = seg ? K1 : K0;
        if (Kd <= 0 || A == nullptr) continue;
        for (int k0 = 0; k0 < Kd; k0 += BK){
            __syncthreads();  // previous tile's ds_reads must drain before restage
            #pragma unroll
            for (int it = 0; it < 4; ++it){   // 1024 chunks of 16B per matrix, 4 per thread
                const int c  = it * 256 + tid;        // LDS chunk index (byte off = c*16)
                const int r  = c >> 3;                // row 0..127
                const int kc = (c & 7) ^ (r & 7);     // swizzled global k-chunk
                async16(A + (size_t)(bm + r) * Kd + k0 + kc * 8, &As[c * 8]);
            }
            #pragma unroll
            for (int it = 0; it < 4; ++it){
                const int c  = it * 256 + tid;
                const int r  = c >> 3;
                const int kc = (c & 7) ^ (r & 7);
                async16(B + (size_t)(bn + r) * Kd + k0 + kc * 8, &Bs[c * 8]);
            }
            __syncthreads();  // s_waitcnt vmcnt(0) before s_barrier -> staging complete
            #pragma unroll
            for (int ks = 0; ks < 2; ++ks){
                short8 af[4], bf[4];
                #pragma unroll
                for (int mi = 0; mi < 4; ++mi){
                    const int row = wm + mi * 16 + l15;
                    const int kq  = ks * 4 + quad;            // k-chunk 0..7
                    af[mi] = *(const short8*)&As[(row * 8 + (kq ^ (row & 7))) * 8];
                }
                #pragma unroll
                for (int ni = 0; ni < 4; ++ni){
                    const int row = wn + ni * 16 + l15;
                    const int kq  = ks * 4 + quad;
                    bf[ni] = *(const short8*)&Bs[(row * 8 + (kq ^ (row & 7))) * 8];
                }
                #pragma unroll
                for (int mi = 0; mi < 4; ++mi)
                    #pragma unroll
                    for (int ni = 0; ni < 4; ++ni)
                        acc[mi][ni] = __builtin_amdgcn_mfma_f32_16x16x32_bf16(
                            af[mi], bf[ni], acc[mi][ni], 0, 0, 0);
            }
        }
    }

    // epilogue: C/D mapping col=lane&15, row=quad*4+reg
    #pragma unroll
    for (int ni = 0; ni < 4; ++ni){
        const int col = bn + wn + ni * 16 + l15;
        float bb = 0.f;
        if (bias0) bb += bias0[col];
        if (bias1) bb += bias1[col];
        #pragma unroll
        for (int mi = 0; mi < 4; ++mi){
            #pragma unroll
            for (int r = 0; r < 4; ++r){
                const int row = bm + wm + mi * 16 + quad * 4 + r;
                float v = acc[mi][ni][r] + bb;
                if (act == 2) v = mish_act(v);
                if (out_bf16) ((unsigned short*)Y)[(size_t)row * N + col] = f2bf(v);
                else          ((float*)Y)[(size_t)row * N + col] = v;
            }
        }
    }
}

// ---------------- fp32 GEMM (small projections):  Y = act(x @ W^T [+ bias]) ----------------
__global__ __launch_bounds__(256) void gemm_xwt(
    const float* __restrict__ A0, const float* __restrict__ B0, int K0,
    const float* __restrict__ bias0,
    float* __restrict__ Y, int N, int act)
{
    __shared__ float As[16][68];
    __shared__ float Bs[16][68];
    const int tid  = threadIdx.x;
    const int bm   = blockIdx.x * 64;
    const int bn   = blockIdx.y * 64;
    const int lrow = tid >> 2;
    const int lk4  = (tid & 3) * 4;
    const int tm   = (tid >> 4) * 4;
    const int tn   = (tid & 15) * 4;
    float acc[4][4] = {};

    const float* aptr = A0 + (size_t)(bm + lrow) * K0 + lk4;
    const float* bptr = B0 + (size_t)(bn + lrow) * K0 + lk4;
    for (int k0 = 0; k0 < K0; k0 += 16){
        const float4 av = *(const float4*)(aptr + k0);
        const float4 bv = *(const float4*)(bptr + k0);
        __syncthreads();
        As[lk4+0][lrow]=av.x; As[lk4+1][lrow]=av.y; As[lk4+2][lrow]=av.z; As[lk4+3][lrow]=av.w;
        Bs[lk4+0][lrow]=bv.x; Bs[lk4+1][lrow]=bv.y; Bs[lk4+2][lrow]=bv.z; Bs[lk4+3][lrow]=bv.w;
        __syncthreads();
        #pragma unroll
        for (int kk = 0; kk < 16; ++kk){
            const float4 a = *(const float4*)&As[kk][tm];
            const float4 b = *(const float4*)&Bs[kk][tn];
            acc[0][0] += a.x*b.x; acc[0][1] += a.x*b.y; acc[0][2] += a.x*b.z; acc[0][3] += a.x*b.w;
            acc[1][0] += a.y*b.x; acc[1][1] += a.y*b.y; acc[1][2] += a.y*b.z; acc[1][3] += a.y*b.w;
            acc[2][0] += a.z*b.x; acc[2][1] += a.z*b.y; acc[2][2] += a.z*b.z; acc[2][3] += a.z*b.w;
            acc[3][0] += a.w*b.x; acc[3][1] += a.w*b.y; acc[3][2] += a.w*b.z; acc[3][3] += a.w*b.w;
        }
    }
    float badd[4] = {0.f, 0.f, 0.f, 0.f};
    if (bias0){
        badd[0] = bias0[bn+tn+0]; badd[1] = bias0[bn+tn+1];
        badd[2] = bias0[bn+tn+2]; badd[3] = bias0[bn+tn+3];
    }
    #pragma unroll
    for (int i = 0; i < 4; ++i){
        float r0 = acc[i][0] + badd[0];
        float r1 = acc[i][1] + badd[1];
        float r2 = acc[i][2] + badd[2];
        float r3 = acc[i][3] + badd[3];
        if (act == 1){ r0 = phi_act(r0); r1 = phi_act(r1); r2 = phi_act(r2); r3 = phi_act(r3); }
        *(float4*)&Y[(size_t)(bm + tm + i) * N + bn + tn] = make_float4(r0, r1, r2, r3);
    }
}

// ---------------- segmented scan, pass A ----------------
__global__ __launch_bounds__(256) void scan_passA(
    const float* __restrict__ kbuf, const float* __restrict__ vbuf,
    const int* __restrict__ start,
    float* __restrict__ chunkS, float* __restrict__ chunkZ, int* __restrict__ chunkFlag)
{
    const int c   = blockIdx.x;
    const int tid = threadIdx.x;
    const int j   = tid >> 2;
    const int i0  = (tid & 3) * 16;
    __shared__ float k_lds[64], v_lds[64];
    float s_loc[16];
    #pragma unroll
    for (int e = 0; e < 16; ++e) s_loc[e] = 0.f;
    float z_loc = 0.f;
    int flag = 0;
    const int t0 = c * CLEN;
    for (int tt = 0; tt < CLEN; ++tt){
        const int t = t0 + tt;
        if (tid < 64)       k_lds[tid]      = kbuf[(size_t)t*K_DIM + tid];
        else if (tid < 128) v_lds[tid - 64] = vbuf[(size_t)t*V_DIM + tid - 64];
        __syncthreads();
        const int st = start[t];
        if (st){
            #pragma unroll
            for (int e = 0; e < 16; ++e) s_loc[e] = 0.f;
            z_loc = 0.f;
            flag = 1;
        }
        const float vj = v_lds[j];
        #pragma unroll
        for (int e = 0; e < 16; ++e) s_loc[e] += k_lds[i0 + e] * vj;
        if (tid < 64) z_loc += k_lds[tid];
        __syncthreads();
    }
    #pragma unroll
    for (int e = 0; e < 16; ++e) chunkS[(size_t)c*4096 + (i0 + e)*64 + j] = s_loc[e];
    if (tid < 64) chunkZ[c*64 + tid] = z_loc;
    if (tid == 0) chunkFlag[c] = flag;
}

// ---------------- pass B: exclusive cross-chunk combine ----------------
__global__ __launch_bounds__(256) void scan_passB(
    const float* __restrict__ chunkS, const float* __restrict__ chunkZ, const int* __restrict__ chunkFlag,
    const float* __restrict__ s0, const float* __restrict__ z0,
    float* __restrict__ carryS, float* __restrict__ carryZ)
{
    const int ij = blockIdx.x * 256 + threadIdx.x;
    float e = s0[ij];
    for (int c = 0; c < CHUNKS; ++c){
        carryS[(size_t)c*4096 + ij] = e;
        const int f   = chunkFlag[c];
        const float s = chunkS[(size_t)c*4096 + ij];
        e = f ? s : (e + s);
    }
    if (ij < 64){
        float ez = z0[ij];
        for (int c = 0; c < CHUNKS; ++c){
            carryZ[c*64 + ij] = ez;
            const int f   = chunkFlag[c];
            const float z = chunkZ[c*64 + ij];
            ez = f ? z : (ez + z);
        }
    }
}

// ---------------- pass C: replay with carry; emit s[t], z[t], att out (bf16) ----------------
__global__ __launch_bounds__(256) void scan_passC(
    const float* __restrict__ kbuf, const float* __restrict__ vbuf, const float* __restrict__ qbuf,
    const int* __restrict__ start,
    const float* __restrict__ carryS, const float* __restrict__ carryZ,
    float* __restrict__ s_out, float* __restrict__ z_out, unsigned short* __restrict__ attout)
{
    const int c   = blockIdx.x;
    const int tid = threadIdx.x;
    const int j   = tid >> 2;
    const int g   = tid & 3;
    const int i0  = g * 16;
    __shared__ float k_lds[64], v_lds[64], q_lds[64];
    __shared__ float numer_lds[64];
    __shared__ float stage[4096];
    float s_loc[16];
    #pragma unroll
    for (int e = 0; e < 16; ++e) s_loc[e] = carryS[(size_t)c*4096 + (i0 + e)*64 + j];
    float z_loc = (tid < 64) ? carryZ[c*64 + tid] : 0.f;

    const int t0 = c * CLEN;
    for (int tt = 0; tt < CLEN; ++tt){
        const int t = t0 + tt;
        if (tid < 64)       k_lds[tid]       = kbuf[(size_t)t*K_DIM + tid];
        else if (tid < 128) v_lds[tid - 64]  = vbuf[(size_t)t*V_DIM + tid - 64];
        else if (tid < 192) q_lds[tid - 128] = qbuf[(size_t)t*K_DIM + tid - 128];
        __syncthreads();
        const int st = start[t];
        if (st){
            #pragma unroll
            for (int e = 0; e < 16; ++e) s_loc[e] = 0.f;
        }
        const float vj = v_lds[j];
        float np = 0.f;
        #pragma unroll
        for (int e = 0; e < 16; ++e){
            s_loc[e] += k_lds[i0 + e] * vj;
            np += s_loc[e] * q_lds[i0 + e];
        }
        np += __shfl_down(np, 1, 64);
        np += __shfl_down(np, 2, 64);
        if (g == 0) numer_lds[j] = np;
        float denom = 1.f;
        if (tid < 64){
            z_loc = (st ? 0.f : z_loc) + k_lds[tid];
            z_out[(size_t)t*K_DIM + tid] = z_loc;
            float zs = z_loc;
            float qs = q_lds[tid];
            #pragma unroll
            for (int o = 32; o > 0; o >>= 1){
                zs += __shfl_down(zs, o, 64);
                qs += __shfl_down(qs, o, 64);
            }
            zs = __shfl(zs, 0, 64);
            qs = __shfl(qs, 0, 64);
            denom = fmaxf(zs * qs, 1e-6f);
        }
        #pragma unroll
        for (int e = 0; e < 16; ++e) stage[(i0 + e)*64 + j] = s_loc[e];
        __syncthreads();
        float4* so = (float4*)(s_out + (size_t)t*4096);
        const float4* stv = (const float4*)stage;
        #pragma unroll
        for (int r = 0; r < 4; ++r) so[tid + 256*r] = stv[tid + 256*r];
        if (tid < 64) attout[(size_t)t*V_DIM + tid] = f2bf(numer_lds[tid] / denom);
        __syncthreads();
    }
}

// ---------------- LayerNorm over H=4096, in place ----------------
__global__ __launch_bounds__(256) void ln_kernel(
    float* __restrict__ h, const float* __restrict__ g, const float* __restrict__ b)
{
    __shared__ float sm[4];
    const int t   = blockIdx.x;
    const int tid = threadIdx.x;
    float* row = h + (size_t)t * H_DIM;
    float4 v[4];
    float s = 0.f;
    #pragma unroll
    for (int r = 0; r < 4; ++r){
        v[r] = ((const float4*)row)[tid + 256*r];
        s += v[r].x + v[r].y + v[r].z + v[r].w;
    }
    #pragma unroll
    for (int o = 32; o > 0; o >>= 1) s += __shfl_down(s, o, 64);
    if ((tid & 63) == 0) sm[tid >> 6] = s;
    __syncthreads();
    const float mu = (sm[0] + sm[1] + sm[2] + sm[3]) * (1.f / H_DIM);
    __syncthreads();
    float sq = 0.f;
    #pragma unroll
    for (int r = 0; r < 4; ++r){
        float dx = v[r].x - mu, dy = v[r].y - mu, dz = v[r].z - mu, dw = v[r].w - mu;
        sq += dx*dx + dy*dy + dz*dz + dw*dw;
    }
    #pragma unroll
    for (int o = 32; o > 0; o >>= 1) sq += __shfl_down(sq, o, 64);
    if ((tid & 63) == 0) sm[tid >> 6] = sq;
    __syncthreads();
    const float var = (sm[0] + sm[1] + sm[2] + sm[3]) * (1.f / H_DIM);
    const float inv = rsqrtf(var + 1e-5f);
    #pragma unroll
    for (int r = 0; r < 4; ++r){
        const int i4 = tid + 256*r;
        const float4 gg = ((const float4*)g)[i4];
        const float4 bb = ((const float4*)b)[i4];
        float4 o;
        o.x = (v[r].x - mu) * inv * gg.x + bb.x;
        o.y = (v[r].y - mu) * inv * gg.y + bb.y;
        o.z = (v[r].z - mu) * inv * gg.z + bb.z;
        o.w = (v[r].w - mu) * inv * gg.w + bb.w;
        ((float4*)row)[i4] = o;
    }
}

extern "C" void kernel_launch(void* const* d_in, const int* in_sizes, int n_in,
                              void* d_out, int out_size, void* d_ws, size_t ws_size,
                              hipStream_t stream)
{
    (void)in_sizes; (void)n_in; (void)out_size; (void)ws_size;
    const float* x     = (const float*)d_in[0];
    const float* s0    = (const float*)d_in[1];
    const float* z0    = (const float*)d_in[2];
    const int*   start = (const int*)d_in[3];
    const float* Wk    = (const float*)d_in[5];
    const float* Wq    = (const float*)d_in[6];
    const float* Wv    = (const float*)d_in[7];
    const float* bv    = (const float*)d_in[8];
    const float* Wskip = (const float*)d_in[9];
    const float* bskip = (const float*)d_in[10];
    const float* W1    = (const float*)d_in[11];
    const float* b1    = (const float*)d_in[12];
    const float* W2    = (const float*)d_in[13];
    const float* b2    = (const float*)d_in[14];
    const float* W3    = (const float*)d_in[15];
    const float* b3    = (const float*)d_in[16];
    const float* ln_g  = (const float*)d_in[17];
    const float* ln_b  = (const float*)d_in[18];

    // ---- workspace carve (256B-aligned), total ~148 MB ----
    char* p = (char*)d_ws;
    auto alloc = [&](size_t bytes) -> void* {
        void* r = (void*)p; p += (bytes + 255) & ~(size_t)255; return r;
    };
    float* kbuf  = (float*)alloc((size_t)T_DIM * K_DIM * 4);
    float* qbuf  = (float*)alloc((size_t)T_DIM * K_DIM * 4);
    float* vbuf  = (float*)alloc((size_t)T_DIM * V_DIM * 4);
    float* chS   = (float*)alloc((size_t)CHUNKS * 4096 * 4);
    float* chZ   = (float*)alloc((size_t)CHUNKS * 64 * 4);
    float* caS   = (float*)alloc((size_t)CHUNKS * 4096 * 4);
    float* caZ   = (float*)alloc((size_t)CHUNKS * 64 * 4);
    int*   flags = (int*)  alloc((size_t)CHUNKS * 4);
    unsigned short* xb     = (unsigned short*)alloc((size_t)T_DIM * IN_DIM * 2);
    unsigned short* Wskipb = (unsigned short*)alloc((size_t)H_DIM * IN_DIM * 2);
    unsigned short* W1b    = (unsigned short*)alloc((size_t)H_DIM * V_DIM * 2);
    unsigned short* W2b    = (unsigned short*)alloc((size_t)H_DIM * H_DIM * 2);
    unsigned short* W3b    = (unsigned short*)alloc((size_t)H_DIM * H_DIM * 2);
    unsigned short* attb   = (unsigned short*)alloc((size_t)T_DIM * V_DIM * 2);
    unsigned short* h1b    = (unsigned short*)alloc((size_t)T_DIM * H_DIM * 2);
    unsigned short* h2b    = (unsigned short*)alloc((size_t)T_DIM * H_DIM * 2);

    float* hn  = (float*)d_out;                          // (T,H)
    float* s_o = hn  + (size_t)T_DIM * H_DIM;            // (T,K,V)
    float* z_o = s_o + (size_t)T_DIM * K_DIM * V_DIM;    // (T,1,K)

    // 0) bf16 conversions of GEMM inputs (independent; launch up front)
    cvt_bf16<<<(T_DIM*IN_DIM/4 + 255)/256, 256, 0, stream>>>(x, xb, T_DIM*IN_DIM/4);
    cvt_bf16<<<(H_DIM*IN_DIM/4 + 255)/256, 256, 0, stream>>>(Wskip, Wskipb, H_DIM*IN_DIM/4);
    cvt_bf16<<<(H_DIM*V_DIM/4 + 255)/256, 256, 0, stream>>>(W1, W1b, H_DIM*V_DIM/4);
    cvt_bf16<<<(H_DIM*H_DIM/4 + 255)/256, 256, 0, stream>>>(W2, W2b, H_DIM*H_DIM/4);
    cvt_bf16<<<(H_DIM*H_DIM/4 + 255)/256, 256, 0, stream>>>(W3, W3b, H_DIM*H_DIM/4);

    // 1) projections (fp32): k = phi(x@Wk^T), q = phi(x@Wq^T), v = x@Wv^T + bv
    gemm_xwt<<<dim3(T_DIM/64, K_DIM/64), 256, 0, stream>>>(x, Wk, IN_DIM, nullptr, kbuf, K_DIM, 1);
    gemm_xwt<<<dim3(T_DIM/64, K_DIM/64), 256, 0, stream>>>(x, Wq, IN_DIM, nullptr, qbuf, K_DIM, 1);
    gemm_xwt<<<dim3(T_DIM/64, V_DIM/64), 256, 0, stream>>>(x, Wv, IN_DIM, bv, vbuf, V_DIM, 0);

    // 2) segmented scan (3 passes); pass C emits att in bf16
    scan_passA<<<CHUNKS, 256, 0, stream>>>(kbuf, vbuf, start, chS, chZ, flags);
    scan_passB<<<4096/256, 256, 0, stream>>>(chS, chZ, flags, s0, z0, caS, caZ);
    scan_passC<<<CHUNKS, 256, 0, stream>>>(kbuf, vbuf, qbuf, start, caS, caZ, s_o, z_o, attb);

    // 3) MLP on bf16 MFMA
    gemm_mfma_bt<<<dim3(T_DIM/128, H_DIM/128), 256, 0, stream>>>(
        attb, W1b, V_DIM, nullptr, nullptr, 0, b1, nullptr, h1b, H_DIM, 2, 1);
    gemm_mfma_bt<<<dim3(T_DIM/128, H_DIM/128), 256, 0, stream>>>(
        h1b, W2b, H_DIM, nullptr, nullptr, 0, b2, nullptr, h2b, H_DIM, 2, 1);
    gemm_mfma_bt<<<dim3(T_DIM/128, H_DIM/128), 256, 0, stream>>>(
        h2b, W3b, H_DIM, xb, Wskipb, IN_DIM, b3, bskip, hn, H_DIM, 0, 0);

    // 4) LayerNorm in place on d_out
    ln_kernel<<<T_DIM, 256, 0, stream>>>(hn, ln_g, ln_b);
}